// Round 19
// baseline (217.975 us; speedup 1.0000x reference)
//
#include <hip/hip_runtime.h>
#include <hip/hip_bf16.h>

#define D 512
#define NSEQ 2048
#define NB 8
#define QBLK 64
#define KVBLK 64
#define NTHREADS 512
#define NT (NSEQ / KVBLK)          // 32 kv tiles
#define ROWE 2112                  // Bs group-row stride (r17: b128 reads <=2-way)
#define BUFE (16 * ROWE)           // 67584 B Bs buffer
#define PROWP 72                   // bf16 row stride for Ps
#define CROWP 68                   // conv transpose tile stride (u16)
#define DEFER_THR 8.0f

typedef __attribute__((ext_vector_type(8))) short bf16x8;
typedef __attribute__((ext_vector_type(4))) float f32x4;
typedef __attribute__((ext_vector_type(4))) unsigned short u16x4;
typedef __attribute__((ext_vector_type(4))) int i32x4;

static __device__ __forceinline__ unsigned short f2b(float f) {
  unsigned u = __builtin_bit_cast(unsigned, f);
  return (unsigned short)((u + 0x7FFFu + ((u >> 16) & 1u)) >> 16);
}

// ------- conv: fp32 B -> b16 [kv][d] AND bT [d][kv] (r11-refcheck'd) --------
__global__ __launch_bounds__(256) void conv_dual(const float* __restrict__ in,
                                                 unsigned short* __restrict__ b16,
                                                 unsigned short* __restrict__ bT) {
  __shared__ unsigned short tile[64 * CROWP];
  const int bid = blockIdx.x;
  const int batch = bid >> 8;
  const int rem = bid & 255;
  const int kvt = rem >> 3;
  const int dt  = rem & 7;
  const int t = threadIdx.x;
  const int r = t >> 2;
  const int c = (t & 3) * 16;

  const float* src = in + ((size_t)batch * NSEQ + kvt * 64 + r) * D + dt * 64 + c;
  unsigned short* o16 = b16 + ((size_t)batch * NSEQ + kvt * 64 + r) * D + dt * 64 + c;

  float4 v0 = *reinterpret_cast<const float4*>(src);
  float4 v1 = *reinterpret_cast<const float4*>(src + 4);
  float4 v2 = *reinterpret_cast<const float4*>(src + 8);
  float4 v3 = *reinterpret_cast<const float4*>(src + 12);
  bf16x8 h0, h1;
  h0[0] = (short)f2b(v0.x); h0[1] = (short)f2b(v0.y);
  h0[2] = (short)f2b(v0.z); h0[3] = (short)f2b(v0.w);
  h0[4] = (short)f2b(v1.x); h0[5] = (short)f2b(v1.y);
  h0[6] = (short)f2b(v1.z); h0[7] = (short)f2b(v1.w);
  h1[0] = (short)f2b(v2.x); h1[1] = (short)f2b(v2.y);
  h1[2] = (short)f2b(v2.z); h1[3] = (short)f2b(v2.w);
  h1[4] = (short)f2b(v3.x); h1[5] = (short)f2b(v3.y);
  h1[6] = (short)f2b(v3.z); h1[7] = (short)f2b(v3.w);
  *reinterpret_cast<bf16x8*>(o16)     = h0;
  *reinterpret_cast<bf16x8*>(o16 + 8) = h1;
  #pragma unroll
  for (int i = 0; i < 4; ++i) {
    u16x4 w;
    w[0] = (unsigned short)((i < 2 ? h0 : h1)[(i & 1) * 4 + 0]);
    w[1] = (unsigned short)((i < 2 ? h0 : h1)[(i & 1) * 4 + 1]);
    w[2] = (unsigned short)((i < 2 ? h0 : h1)[(i & 1) * 4 + 2]);
    w[3] = (unsigned short)((i < 2 ? h0 : h1)[(i & 1) * 4 + 3]);
    *reinterpret_cast<u16x4*>(&tile[r * CROWP + c + i * 4]) = w;
  }
  __syncthreads();

  const int w  = t >> 6;
  const int dr = t & 63;
  unsigned short* oT = bT + (size_t)batch * D * NSEQ
                          + (size_t)(dt * 64 + dr) * NSEQ + kvt * 64 + w * 16;
  unsigned short g[16];
  #pragma unroll
  for (int i = 0; i < 16; ++i)
    g[i] = tile[(w * 16 + i) * CROWP + dr];
  bf16x8 p0, p1;
  #pragma unroll
  for (int i = 0; i < 8; ++i) { p0[i] = (short)g[i]; p1[i] = (short)g[8 + i]; }
  *reinterpret_cast<bf16x8*>(oT)     = p0;
  *reinterpret_cast<bf16x8*>(oT + 8) = p1;
}

// ---------------------------- v19 main kernel -------------------------------
// = v18 (131us) with wave remap (1q x 2kv) -> (2q x 1kv): wave w has kv-tile
// k=w>>1, q-tiles 2(w&1), 2(w&1)+1. Each B-frag b128 read feeds TWO MFMAs
// (s0 w/ qf0, s1 w/ qf1) -> QK^T Bs reads halve: 256 -> 128 b128/CU/tile.
// Q doubles to qf0+qf1 = 128 VGPR (budget 256/wave at 2 waves/SIMD).
// Softmax: per q-row, 4 kv-partials combined via pmaxS/psumS[4][64] (fixed
// combine order -> all waves converge to identical mnew; stats written by
// k==0 waves only; mS race benign as in v18). PV/DMA/vmcnt/epilogue verbatim.
__global__ __launch_bounds__(NTHREADS, 1)
void attn_v19(const float* __restrict__ A, const unsigned short* __restrict__ B16,
              const unsigned short* __restrict__ T16, float* __restrict__ Out) {
  __shared__ __align__(16) unsigned short Bs[BUFE];          // [kv][d] subtiled
  __shared__ __align__(16) unsigned short Bt[D * KVBLK];     // [d][kv] swizzled
  __shared__ __align__(16) unsigned short Ps[QBLK * PROWP];
  __shared__ float mS[QBLK];
  __shared__ float lS[QBLK];
  __shared__ float aS[QBLK];
  __shared__ float pmaxS[4 * 64];   // [kv-tile][q-row]
  __shared__ float psumS[4 * 64];
  __shared__ __align__(16) int flagS[8];

  const int tid  = threadIdx.x;
  const int wid  = tid >> 6;
  const int lane = tid & 63;
  const int l16  = lane & 15;
  const int g4   = lane >> 4;

  const int batch = blockIdx.x & 7;       // batch -> XCD (L2 locality)
  const int qt    = blockIdx.x >> 3;      // 0..31
  const int qbase = qt * QBLK;

  const float*          Ab = A   + (size_t)batch * NSEQ * D;
  const unsigned short* Kb = B16 + (size_t)batch * NSEQ * D;
  const unsigned short* Tb = T16 + (size_t)batch * D * NSEQ;
  float*                Ob = Out + (size_t)batch * NSEQ * D;

  const float scale = 0.04419417382415922f;  // 1/sqrt(512)

  const int kvt = wid >> 1;  // wave's kv 16-tile (0..3)
  const int qp  = wid & 1;   // wave's q pair: q-tiles qp*2, qp*2+1
  const int t0  = qp * 2, t1 = qp * 2 + 1;

  // ---- TWO Q tiles into registers (pre-scaled) ----
  bf16x8 qf0[16], qf1[16];
  {
    const float* Ar0 = Ab + (size_t)(qbase + t0 * 16 + l16) * D;
    const float* Ar1 = Ab + (size_t)(qbase + t1 * 16 + l16) * D;
    #pragma unroll
    for (int ks = 0; ks < 16; ++ks) {
      int d0 = ks * 32 + g4 * 8;
      float4 a0 = *reinterpret_cast<const float4*>(Ar0 + d0);
      float4 a1 = *reinterpret_cast<const float4*>(Ar0 + d0 + 4);
      float4 b0 = *reinterpret_cast<const float4*>(Ar1 + d0);
      float4 b1 = *reinterpret_cast<const float4*>(Ar1 + d0 + 4);
      bf16x8 f0, f1;
      f0[0] = (short)f2b(a0.x * scale); f0[1] = (short)f2b(a0.y * scale);
      f0[2] = (short)f2b(a0.z * scale); f0[3] = (short)f2b(a0.w * scale);
      f0[4] = (short)f2b(a1.x * scale); f0[5] = (short)f2b(a1.y * scale);
      f0[6] = (short)f2b(a1.z * scale); f0[7] = (short)f2b(a1.w * scale);
      f1[0] = (short)f2b(b0.x * scale); f1[1] = (short)f2b(b0.y * scale);
      f1[2] = (short)f2b(b0.z * scale); f1[3] = (short)f2b(b0.w * scale);
      f1[4] = (short)f2b(b1.x * scale); f1[5] = (short)f2b(b1.y * scale);
      f1[6] = (short)f2b(b1.z * scale); f1[7] = (short)f2b(b1.w * scale);
      qf0[ks] = f0;
      qf1[ks] = f1;
    }
  }
  if (tid < QBLK) { mS[tid] = -1e30f; lS[tid] = 0.f; }

  f32x4 acc[4][4];
  #pragma unroll
  for (int mi = 0; mi < 4; ++mi)
    #pragma unroll
    for (int ni = 0; ni < 4; ++ni)
      acc[mi][ni] = (f32x4){0.f, 0.f, 0.f, 0.f};

  // ---- prologue: DMA Bs(0) + Bt(0), full drain ----
  #pragma unroll
  for (int c = 0; c < 8; ++c) {
    int id = wid * 8 + c;
    int g = id >> 2, q = id & 3;
    const unsigned short* src = Kb
        + (size_t)(g * 4 + ((lane >> 1) & 3)) * D
        + q * 128 + (lane >> 3) * 16 + (lane & 1) * 8;
    unsigned short* dst = &Bs[g * ROWE + q * 512];
    __builtin_amdgcn_global_load_lds(
        (const __attribute__((address_space(1))) void*)src,
        (__attribute__((address_space(3))) void*)dst, 16, 0, 0);
  }
  #pragma unroll
  for (int c = 0; c < 8; ++c) {
    int drow = wid * 64 + c * 8 + (lane >> 3);
    int chunk = (lane & 7) ^ ((lane >> 3) & 7);
    const unsigned short* src = Tb + (size_t)drow * NSEQ + chunk * 8;
    unsigned short* dst = (unsigned short*)&Bt[(wid * 64 + c * 8) * KVBLK];
    __builtin_amdgcn_global_load_lds(
        (const __attribute__((address_space(1))) void*)src,
        (__attribute__((address_space(3))) void*)dst, 16, 0, 0);
  }
  asm volatile("s_waitcnt vmcnt(0)" ::: "memory");
  asm volatile("s_waitcnt lgkmcnt(0)" ::: "memory");
  __builtin_amdgcn_s_barrier();

  const int bbase = (kvt * 4 + (l16 >> 2)) * ROWE + (l16 & 3) * 16 + (g4 & 1) * 8;

  for (int kt = 0; kt < NT; ++kt) {
    // ---- swapped QK^T: one B-frag feeds 2 MFMAs (q-tiles t0, t1) ----
    f32x4 s0 = {0.f, 0.f, 0.f, 0.f};   // S^T: col = q(t0) = l16, row = kv = 4g4+r
    f32x4 s1 = {0.f, 0.f, 0.f, 0.f};   // q-tile t1
    __builtin_amdgcn_s_setprio(1);
    #pragma unroll
    for (int ks = 0; ks < 16; ++ks) {
      const int ro = (ks * 2 + (g4 >> 1)) * 64;
      const bf16x8 b = *reinterpret_cast<const bf16x8*>(&Bs[bbase + ro]);
      s0 = __builtin_amdgcn_mfma_f32_16x16x32_bf16(b, qf0[ks], s0, 0, 0, 0);
      s1 = __builtin_amdgcn_mfma_f32_16x16x32_bf16(b, qf1[ks], s1, 0, 0, 0);
    }
    __builtin_amdgcn_s_setprio(0);

    // ---- per-q-row partial max over this wave's 16 kv ----
    float mloc0, mloc1;
    {
      float a01 = fmaxf(s0[0], s0[1]), a23 = fmaxf(s0[2], s0[3]);
      float b01 = fmaxf(s1[0], s1[1]), b23 = fmaxf(s1[2], s1[3]);
      mloc0 = fmaxf(a01, a23);
      mloc1 = fmaxf(b01, b23);
      mloc0 = fmaxf(mloc0, __shfl_xor(mloc0, 16));
      mloc0 = fmaxf(mloc0, __shfl_xor(mloc0, 32));
      mloc1 = fmaxf(mloc1, __shfl_xor(mloc1, 16));
      mloc1 = fmaxf(mloc1, __shfl_xor(mloc1, 32));
      if (lane < 32) {
        int t = (lane < 16) ? t0 : t1;
        float v = (lane < 16) ? mloc0 : mloc1;
        pmaxS[kvt * 64 + t * 16 + l16] = v;
      }
    }
    asm volatile("s_waitcnt lgkmcnt(0)" ::: "memory");
    __builtin_amdgcn_s_barrier();           // 1: Bs reads done; pmax visible

    // ---- issue Bs(kt+1): lands under exp/PV ----
    if (kt + 1 < NT) {
      const unsigned short* Kt = Kb + (size_t)(kt + 1) * KVBLK * D;
      #pragma unroll
      for (int c = 0; c < 8; ++c) {
        int id = wid * 8 + c;
        int g = id >> 2, q = id & 3;
        const unsigned short* src = Kt
            + (size_t)(g * 4 + ((lane >> 1) & 3)) * D
            + q * 128 + (lane >> 3) * 16 + (lane & 1) * 8;
        unsigned short* dst = &Bs[g * ROWE + q * 512];
        __builtin_amdgcn_global_load_lds(
            (const __attribute__((address_space(1))) void*)src,
            (__attribute__((address_space(3))) void*)dst, 16, 0, 0);
      }
    }

    // ---- combine 4 kv partials (fixed order), defer, exp, Ps, psum ----
    float al0, al1, rowsum0, rowsum1;
    int defer0, defer1;
    {
      const int row0 = t0 * 16 + l16, row1 = t1 * 16 + l16;
      float p0a = pmaxS[0 * 64 + row0], p0b = pmaxS[1 * 64 + row0];
      float p0c = pmaxS[2 * 64 + row0], p0d = pmaxS[3 * 64 + row0];
      float p1a = pmaxS[0 * 64 + row1], p1b = pmaxS[1 * 64 + row1];
      float p1c = pmaxS[2 * 64 + row1], p1d = pmaxS[3 * 64 + row1];
      float mc0 = fmaxf(fmaxf(p0a, p0b), fmaxf(p0c, p0d));
      float mc1 = fmaxf(fmaxf(p1a, p1b), fmaxf(p1c, p1d));
      float mold0 = mS[row0], mold1 = mS[row1];
      defer0 = (mc0 <= mold0 + DEFER_THR) ? 1 : 0;
      defer1 = (mc1 <= mold1 + DEFER_THR) ? 1 : 0;
      float mnew0 = defer0 ? mold0 : mc0;
      float mnew1 = defer1 ? mold1 : mc1;
      al0 = defer0 ? 1.0f : __expf(mold0 - mnew0);
      al1 = defer1 ? 1.0f : __expf(mold1 - mnew1);

      rowsum0 = 0.f; rowsum1 = 0.f;
      u16x4 w0, w1;
      #pragma unroll
      for (int r = 0; r < 4; ++r) {
        float p = __expf(s0[r] - mnew0);
        rowsum0 += p;
        w0[r] = f2b(p);
      }
      #pragma unroll
      for (int r = 0; r < 4; ++r) {
        float p = __expf(s1[r] - mnew1);
        rowsum1 += p;
        w1[r] = f2b(p);
      }
      const int kvoff = kvt * 16 + 4 * g4;
      *reinterpret_cast<u16x4*>(&Ps[row0 * PROWP + kvoff]) = w0;
      *reinterpret_cast<u16x4*>(&Ps[row1 * PROWP + kvoff]) = w1;

      rowsum0 += __shfl_xor(rowsum0, 16);
      rowsum0 += __shfl_xor(rowsum0, 32);
      rowsum1 += __shfl_xor(rowsum1, 16);
      rowsum1 += __shfl_xor(rowsum1, 32);
      if (lane < 32) {
        int t = (lane < 16) ? t0 : t1;
        float v = (lane < 16) ? rowsum0 : rowsum1;
        psumS[kvt * 64 + t * 16 + l16] = v;
      }
      int wave_defer = __all(defer0 & defer1);
      if (kvt == 0 && lane < 32) {
        int row = ((lane < 16) ? t0 : t1) * 16 + l16;
        mS[row] = (lane < 16) ? mnew0 : mnew1;
        aS[row] = (lane < 16) ? al0 : al1;
      }
      if (lane == 0) flagS[wid] = wave_defer;
    }
    asm volatile("s_waitcnt lgkmcnt(0)" ::: "memory");
    if (kt + 1 < NT) {
      asm volatile("s_waitcnt vmcnt(8)" ::: "memory");  // Bt(kt) landed
    } else {
      asm volatile("s_waitcnt vmcnt(0)" ::: "memory");
    }
    __builtin_amdgcn_s_barrier();           // 2: Ps/psum/aS/flags + Bt(kt)

    // ---- lS combine (k==0 waves; psumS stable until next barrier 1) ----
    if (kvt == 0 && lane < 32) {
      int row = ((lane < 16) ? t0 : t1) * 16 + l16;
      float al = (lane < 16) ? al0 : al1;
      float sum4 = psumS[0 * 64 + row] + psumS[1 * 64 + row]
                 + psumS[2 * 64 + row] + psumS[3 * 64 + row];
      lS[row] = lS[row] * al + sum4;
    }

    // ---- conditional rescale + PV: O^T += V^T * P^T (r11 verbatim) ----
    {
      i32x4 f0 = *reinterpret_cast<const i32x4*>(&flagS[0]);
      i32x4 f1 = *reinterpret_cast<const i32x4*>(&flagS[4]);
      int allskip = f0[0] & f0[1] & f0[2] & f0[3] & f1[0] & f1[1] & f1[2] & f1[3];
      if (!allskip) {
        #pragma unroll
        for (int mi = 0; mi < 4; ++mi) {
          float a = aS[mi * 16 + l16];
          #pragma unroll
          for (int ni = 0; ni < 4; ++ni)
            #pragma unroll
            for (int r = 0; r < 4; ++r)
              acc[mi][ni][r] *= a;
        }
      }

      const char* Bc = (const char*)&Bt[0];
      __builtin_amdgcn_s_setprio(1);
      #pragma unroll
      for (int ks = 0; ks < 2; ++ks) {
        bf16x8 pf[4];
        #pragma unroll
        for (int mi = 0; mi < 4; ++mi)
          pf[mi] = *reinterpret_cast<const bf16x8*>(
              &Ps[(mi * 16 + l16) * PROWP + ks * 32 + g4 * 8]);
        #pragma unroll
        for (int ni = 0; ni < 4; ++ni) {
          int row = wid * 64 + ni * 16 + l16;
          int swz = (ks * 4 + g4) ^ (l16 & 7);
          const bf16x8 vf = *reinterpret_cast<const bf16x8*>(Bc + row * 128 + swz * 16);
          #pragma unroll
          for (int mi = 0; mi < 4; ++mi)
            acc[mi][ni] = __builtin_amdgcn_mfma_f32_16x16x32_bf16(vf, pf[mi], acc[mi][ni], 0, 0, 0);
        }
      }
      __builtin_amdgcn_s_setprio(0);
    }
    // own Bt reads complete (Bt is wave-private: no barrier before re-issue)
    asm volatile("s_waitcnt lgkmcnt(0)" ::: "memory");

    // ---- issue Bt(kt+1); wait Bs(kt+1) landed (oldest 8 of 16) ----
    if (kt + 1 < NT) {
      #pragma unroll
      for (int c = 0; c < 8; ++c) {
        int drow = wid * 64 + c * 8 + (lane >> 3);
        int chunk = (lane & 7) ^ ((lane >> 3) & 7);
        const unsigned short* src = Tb + (size_t)drow * NSEQ + (kt + 1) * KVBLK + chunk * 8;
        unsigned short* dst = (unsigned short*)&Bt[(wid * 64 + c * 8) * KVBLK];
        __builtin_amdgcn_global_load_lds(
            (const __attribute__((address_space(1))) void*)src,
            (__attribute__((address_space(3))) void*)dst, 16, 0, 0);
      }
      asm volatile("s_waitcnt vmcnt(8)" ::: "memory");
    }
    __builtin_amdgcn_s_barrier();           // D: Bs(kt+1) ready
  }

  // ---- epilogue: Out[q][d] = accT/l + A[q][d] (r11 verbatim) ----
  #pragma unroll
  for (int mi = 0; mi < 4; ++mi) {
    float rl = 1.0f / lS[mi * 16 + l16];
    int q = qbase + mi * 16 + l16;
    #pragma unroll
    for (int ni = 0; ni < 4; ++ni) {
      int d = wid * 64 + ni * 16 + g4 * 4;
      const float4 av = *reinterpret_cast<const float4*>(Ab + (size_t)q * D + d);
      float4 o;
      o.x = acc[mi][ni][0] * rl + av.x;
      o.y = acc[mi][ni][1] * rl + av.y;
      o.z = acc[mi][ni][2] * rl + av.z;
      o.w = acc[mi][ni][3] * rl + av.w;
      *reinterpret_cast<float4*>(Ob + (size_t)q * D + d) = o;
    }
  }
}

// ---------- fallback: in-kernel convert staging (no workspace) --------------
#define FQBLK 32
#define FSROWP (64 + 4)
#define FPROWP (64 + 8)
__global__ __launch_bounds__(NTHREADS, 2)
void attn_fb(const float* __restrict__ A, const float* __restrict__ B32,
             float* __restrict__ Out) {
  __shared__ __align__(16) unsigned short Bs[BUFE];
  __shared__ float Ss[FQBLK * FSROWP];
  __shared__ unsigned short Ps[FQBLK * FPROWP];
  __shared__ float mS[FQBLK];
  __shared__ float lS[FQBLK];
  __shared__ float aS[FQBLK];

  const int tid  = threadIdx.x;
  const int wid  = tid >> 6;
  const int lane = tid & 63;
  const int l16  = lane & 15;
  const int g4   = lane >> 4;

  const int batch = blockIdx.x & 7;
  const int qt    = blockIdx.x >> 3;
  const int qbase = qt * FQBLK;

  const float* Ab   = A   + (size_t)batch * NSEQ * D;
  const float* Bb32 = B32 + (size_t)batch * NSEQ * D;
  float*       Ob   = Out + (size_t)batch * NSEQ * D;

  const float scale = 0.04419417382415922f;

  const int qi = wid >> 2;
  const int ki = wid & 3;

  const float* Arow = Ab + (size_t)(qbase + qi * 16 + l16) * D;
  bf16x8 qf[16];
  #pragma unroll
  for (int ks = 0; ks < 16; ++ks) {
    int d0 = ks * 32 + g4 * 8;
    float4 v0 = *reinterpret_cast<const float4*>(Arow + d0);
    float4 v1 = *reinterpret_cast<const float4*>(Arow + d0 + 4);
    bf16x8 f;
    f[0] = (short)f2b(v0.x * scale); f[1] = (short)f2b(v0.y * scale);
    f[2] = (short)f2b(v0.z * scale); f[3] = (short)f2b(v0.w * scale);
    f[4] = (short)f2b(v1.x * scale); f[5] = (short)f2b(v1.y * scale);
    f[6] = (short)f2b(v1.z * scale); f[7] = (short)f2b(v1.w * scale);
    qf[ks] = f;
  }
  if (tid < FQBLK) { mS[tid] = -1e30f; lS[tid] = 0.f; }

  f32x4 acc[2][4];
  #pragma unroll
  for (int mi = 0; mi < 2; ++mi)
    #pragma unroll
    for (int ni = 0; ni < 4; ++ni)
      acc[mi][ni] = (f32x4){0.f, 0.f, 0.f, 0.f};

  for (int kt = 0; kt < NT; ++kt) {
    __builtin_amdgcn_s_barrier();
    const float* Bt2 = Bb32 + (size_t)kt * KVBLK * D;
    #pragma unroll
    for (int c = 0; c < 8; ++c) {
      int id = wid * 8 + c;
      int g = id >> 2, q = id & 3;
      int kv = g * 4 + ((lane >> 1) & 3);
      int d  = q * 128 + (lane >> 3) * 16 + (lane & 1) * 8;
      const float* s = Bt2 + (size_t)kv * D + d;
      float4 v0 = *reinterpret_cast<const float4*>(s);
      float4 v1 = *reinterpret_cast<const float4*>(s + 4);
      bf16x8 h;
      h[0] = (short)f2b(v0.x); h[1] = (short)f2b(v0.y);
      h[2] = (short)f2b(v0.z); h[3] = (short)f2b(v0.w);
      h[4] = (short)f2b(v1.x); h[5] = (short)f2b(v1.y);
      h[6] = (short)f2b(v1.z); h[7] = (short)f2b(v1.w);
      *reinterpret_cast<bf16x8*>(&Bs[g * ROWE + q * 512 + lane * 8]) = h;
    }
    asm volatile("s_waitcnt lgkmcnt(0)" ::: "memory");
    __builtin_amdgcn_s_barrier();

    {
      f32x4 s = {0.f, 0.f, 0.f, 0.f};
      const int bbase = (ki * 4 + (l16 >> 2)) * ROWE + (l16 & 3) * 16 + (g4 & 1) * 8;
      #pragma unroll
      for (int ks = 0; ks < 16; ++ks) {
        const bf16x8 bf = *reinterpret_cast<const bf16x8*>(
            &Bs[bbase + (ks * 2 + (g4 >> 1)) * 64]);
        s = __builtin_amdgcn_mfma_f32_16x16x32_bf16(qf[ks], bf, s, 0, 0, 0);
      }
      #pragma unroll
      for (int r = 0; r < 4; ++r)
        Ss[(qi * 16 + g4 * 4 + r) * FSROWP + ki * 16 + l16] = s[r];
    }
    asm volatile("s_waitcnt lgkmcnt(0)" ::: "memory");
    __builtin_amdgcn_s_barrier();

    {
      int row = wid * 4 + g4;
      float sv[4];
      float mloc = -1e30f;
      #pragma unroll
      for (int j = 0; j < 4; ++j) {
        sv[j] = Ss[row * FSROWP + l16 + 16 * j];
        mloc = fmaxf(mloc, sv[j]);
      }
      #pragma unroll
      for (int off = 1; off < 16; off <<= 1)
        mloc = fmaxf(mloc, __shfl_xor(mloc, off));
      float mold = mS[row];
      float mnew = fmaxf(mold, mloc);
      float al = __expf(mold - mnew);
      float psum = 0.f;
      #pragma unroll
      for (int j = 0; j < 4; ++j) {
        float p = __expf(sv[j] - mnew);
        psum += p;
        Ps[row * FPROWP + l16 + 16 * j] = f2b(p);
      }
      #pragma unroll
      for (int off = 1; off < 16; off <<= 1)
        psum += __shfl_xor(psum, off);
      if (l16 == 0) {
        mS[row] = mnew;
        lS[row] = lS[row] * al + psum;
        aS[row] = al;
      }
    }
    asm volatile("s_waitcnt lgkmcnt(0)" ::: "memory");
    __builtin_amdgcn_s_barrier();

    {
      #pragma unroll
      for (int mi = 0; mi < 2; ++mi)
        #pragma unroll
        for (int r = 0; r < 4; ++r) {
          float a = aS[mi * 16 + g4 * 4 + r];
          #pragma unroll
          for (int ni = 0; ni < 4; ++ni)
            acc[mi][ni][r] *= a;
        }

      #pragma unroll
      for (int ks = 0; ks < 2; ++ks) {
        bf16x8 pf[2];
        #pragma unroll
        for (int mi = 0; mi < 2; ++mi)
          pf[mi] = *reinterpret_cast<const bf16x8*>(
              &Ps[(mi * 16 + l16) * FPROWP + ks * 32 + g4 * 8]);
        #pragma unroll
        for (int ni = 0; ni < 4; ++ni) {
          bf16x8 vv;
          #pragma unroll
          for (int j = 0; j < 8; ++j)
            vv[j] = (short)Bs[(ks * 8 + g4 * 2 + (j >> 2)) * ROWE
                              + (wid * 4 + ni) * 64 + (j & 3) * 16 + l16];
          #pragma unroll
          for (int mi = 0; mi < 2; ++mi)
            acc[mi][ni] = __builtin_amdgcn_mfma_f32_16x16x32_bf16(pf[mi], vv, acc[mi][ni], 0, 0, 0);
        }
      }
    }
  }

  #pragma unroll
  for (int mi = 0; mi < 2; ++mi)
    #pragma unroll
    for (int r = 0; r < 4; ++r) {
      float rl = 1.0f / lS[mi * 16 + g4 * 4 + r];
      #pragma unroll
      for (int ni = 0; ni < 4; ++ni) {
        int q = qbase + mi * 16 + g4 * 4 + r;
        int d = wid * 64 + ni * 16 + l16;
        size_t off = (size_t)q * D + d;
        Ob[off] = acc[mi][ni][r] * rl + Ab[off];
      }
    }
}

extern "C" void kernel_launch(void* const* d_in, const int* in_sizes, int n_in,
                              void* d_out, int out_size, void* d_ws, size_t ws_size,
                              hipStream_t stream) {
  const float* a = (const float*)d_in[0];
  const float* b = (const float*)d_in[1];
  float* out = (float*)d_out;
  const size_t one = (size_t)NB * NSEQ * D * sizeof(unsigned short);  // 16 MB
  dim3 block(NTHREADS);
  if (ws_size >= 2 * one) {
    unsigned short* b16 = (unsigned short*)d_ws;
    unsigned short* bT  = b16 + (size_t)NB * NSEQ * D;
    conv_dual<<<NB * 256, 256, 0, stream>>>(b, b16, bT);
    dim3 grid(NB * (NSEQ / QBLK));            // 256 blocks = 1 per CU
    attn_v19<<<grid, block, 0, stream>>>(a, b16, bT, out);
  } else {
    dim3 grid(NB * (NSEQ / FQBLK));
    attn_fb<<<grid, block, 0, stream>>>(a, b, out);
  }
}

// Round 20
// 131.115 us; speedup vs baseline: 1.6625x; 1.6625x over previous
//
#include <hip/hip_runtime.h>
#include <hip/hip_bf16.h>

#define D 512
#define NSEQ 2048
#define NB 8
#define QBLK 64
#define KVBLK 64
#define NTHREADS 512
#define NT (NSEQ / KVBLK)          // 32 kv tiles
#define ROWE 2112                  // Bs group-row stride (r17: b128 reads <=2-way)
#define BUFE (16 * ROWE)           // 67584 B Bs buffer
#define PROWP 72                   // bf16 row stride for Ps
#define CROWP 68                   // conv transpose tile stride (u16)
#define DEFER_THR 8.0f

typedef __attribute__((ext_vector_type(8))) short bf16x8;
typedef __attribute__((ext_vector_type(4))) float f32x4;
typedef __attribute__((ext_vector_type(4))) unsigned short u16x4;
typedef __attribute__((ext_vector_type(4))) int i32x4;

static __device__ __forceinline__ unsigned short f2b(float f) {
  unsigned u = __builtin_bit_cast(unsigned, f);
  return (unsigned short)((u + 0x7FFFu + ((u >> 16) & 1u)) >> 16);
}

// ------- conv: fp32 B -> b16 [kv][d] AND bT [d][kv] (r11-refcheck'd) --------
__global__ __launch_bounds__(256) void conv_dual(const float* __restrict__ in,
                                                 unsigned short* __restrict__ b16,
                                                 unsigned short* __restrict__ bT) {
  __shared__ unsigned short tile[64 * CROWP];
  const int bid = blockIdx.x;
  const int batch = bid >> 8;
  const int rem = bid & 255;
  const int kvt = rem >> 3;
  const int dt  = rem & 7;
  const int t = threadIdx.x;
  const int r = t >> 2;
  const int c = (t & 3) * 16;

  const float* src = in + ((size_t)batch * NSEQ + kvt * 64 + r) * D + dt * 64 + c;
  unsigned short* o16 = b16 + ((size_t)batch * NSEQ + kvt * 64 + r) * D + dt * 64 + c;

  float4 v0 = *reinterpret_cast<const float4*>(src);
  float4 v1 = *reinterpret_cast<const float4*>(src + 4);
  float4 v2 = *reinterpret_cast<const float4*>(src + 8);
  float4 v3 = *reinterpret_cast<const float4*>(src + 12);
  bf16x8 h0, h1;
  h0[0] = (short)f2b(v0.x); h0[1] = (short)f2b(v0.y);
  h0[2] = (short)f2b(v0.z); h0[3] = (short)f2b(v0.w);
  h0[4] = (short)f2b(v1.x); h0[5] = (short)f2b(v1.y);
  h0[6] = (short)f2b(v1.z); h0[7] = (short)f2b(v1.w);
  h1[0] = (short)f2b(v2.x); h1[1] = (short)f2b(v2.y);
  h1[2] = (short)f2b(v2.z); h1[3] = (short)f2b(v2.w);
  h1[4] = (short)f2b(v3.x); h1[5] = (short)f2b(v3.y);
  h1[6] = (short)f2b(v3.z); h1[7] = (short)f2b(v3.w);
  *reinterpret_cast<bf16x8*>(o16)     = h0;
  *reinterpret_cast<bf16x8*>(o16 + 8) = h1;
  #pragma unroll
  for (int i = 0; i < 4; ++i) {
    u16x4 w;
    w[0] = (unsigned short)((i < 2 ? h0 : h1)[(i & 1) * 4 + 0]);
    w[1] = (unsigned short)((i < 2 ? h0 : h1)[(i & 1) * 4 + 1]);
    w[2] = (unsigned short)((i < 2 ? h0 : h1)[(i & 1) * 4 + 2]);
    w[3] = (unsigned short)((i < 2 ? h0 : h1)[(i & 1) * 4 + 3]);
    *reinterpret_cast<u16x4*>(&tile[r * CROWP + c + i * 4]) = w;
  }
  __syncthreads();

  const int w  = t >> 6;
  const int dr = t & 63;
  unsigned short* oT = bT + (size_t)batch * D * NSEQ
                          + (size_t)(dt * 64 + dr) * NSEQ + kvt * 64 + w * 16;
  unsigned short g[16];
  #pragma unroll
  for (int i = 0; i < 16; ++i)
    g[i] = tile[(w * 16 + i) * CROWP + dr];
  bf16x8 p0, p1;
  #pragma unroll
  for (int i = 0; i < 8; ++i) { p0[i] = (short)g[i]; p1[i] = (short)g[8 + i]; }
  *reinterpret_cast<bf16x8*>(oT)     = p0;
  *reinterpret_cast<bf16x8*>(oT + 8) = p1;
}

// ---------------------------- v20 = v18 (best verified, 131us) --------------
// r19 post-mortem: (2q x 1kv) remap needs 128 Q-regs; hipcc pins arch VGPRs
// at 128 for 512-thread blocks (3rd confirmation: r4, r8, r19) -> 63MB spill,
// 218us. REFUTED. This restores v18: swapped QK^T + in-register softmax +
// defer-max + wave-private Bt + counted vmcnt(8) + ROWE=2112 conflict-free Bs.
__global__ __launch_bounds__(NTHREADS, 1)
void attn_v18(const float* __restrict__ A, const unsigned short* __restrict__ B16,
              const unsigned short* __restrict__ T16, float* __restrict__ Out) {
  __shared__ __align__(16) unsigned short Bs[BUFE];          // [kv][d] subtiled
  __shared__ __align__(16) unsigned short Bt[D * KVBLK];     // [d][kv] swizzled
  __shared__ __align__(16) unsigned short Ps[QBLK * PROWP];
  __shared__ float mS[QBLK];
  __shared__ float lS[QBLK];
  __shared__ float aS[QBLK];
  __shared__ float pmaxS[128];    // [qi][kp][l16]
  __shared__ float psumS[128];
  __shared__ __align__(16) int flagS[8];

  const int tid  = threadIdx.x;
  const int wid  = tid >> 6;
  const int lane = tid & 63;
  const int l16  = lane & 15;
  const int g4   = lane >> 4;

  const int batch = blockIdx.x & 7;       // batch -> XCD (L2 locality)
  const int qt    = blockIdx.x >> 3;      // 0..31
  const int qbase = qt * QBLK;

  const float*          Ab = A   + (size_t)batch * NSEQ * D;
  const unsigned short* Kb = B16 + (size_t)batch * NSEQ * D;
  const unsigned short* Tb = T16 + (size_t)batch * D * NSEQ;
  float*                Ob = Out + (size_t)batch * NSEQ * D;

  const float scale = 0.04419417382415922f;  // 1/sqrt(512)

  const int qi = wid >> 1;   // wave's q 16-tile (0..3)
  const int kp = wid & 1;    // wave's kv pair: kv-tiles kp*2, kp*2+1

  // ---- Q tile into registers (pre-scaled), v4/v5-verified pattern ----
  const float* Arow = Ab + (size_t)(qbase + qi * 16 + l16) * D;
  bf16x8 qf[16];
  #pragma unroll
  for (int ks = 0; ks < 16; ++ks) {
    int d0 = ks * 32 + g4 * 8;
    float4 v0 = *reinterpret_cast<const float4*>(Arow + d0);
    float4 v1 = *reinterpret_cast<const float4*>(Arow + d0 + 4);
    bf16x8 f;
    f[0] = (short)f2b(v0.x * scale); f[1] = (short)f2b(v0.y * scale);
    f[2] = (short)f2b(v0.z * scale); f[3] = (short)f2b(v0.w * scale);
    f[4] = (short)f2b(v1.x * scale); f[5] = (short)f2b(v1.y * scale);
    f[6] = (short)f2b(v1.z * scale); f[7] = (short)f2b(v1.w * scale);
    qf[ks] = f;
  }
  if (tid < QBLK) { mS[tid] = -1e30f; lS[tid] = 0.f; }

  f32x4 acc[4][4];
  #pragma unroll
  for (int mi = 0; mi < 4; ++mi)
    #pragma unroll
    for (int ni = 0; ni < 4; ++ni)
      acc[mi][ni] = (f32x4){0.f, 0.f, 0.f, 0.f};

  // ---- prologue: DMA Bs(0) + Bt(0), full drain ----
  #pragma unroll
  for (int c = 0; c < 8; ++c) {
    int id = wid * 8 + c;
    int g = id >> 2, q = id & 3;
    const unsigned short* src = Kb
        + (size_t)(g * 4 + ((lane >> 1) & 3)) * D
        + q * 128 + (lane >> 3) * 16 + (lane & 1) * 8;
    unsigned short* dst = &Bs[g * ROWE + q * 512];
    __builtin_amdgcn_global_load_lds(
        (const __attribute__((address_space(1))) void*)src,
        (__attribute__((address_space(3))) void*)dst, 16, 0, 0);
  }
  #pragma unroll
  for (int c = 0; c < 8; ++c) {
    int drow = wid * 64 + c * 8 + (lane >> 3);
    int chunk = (lane & 7) ^ ((lane >> 3) & 7);
    const unsigned short* src = Tb + (size_t)drow * NSEQ + chunk * 8;
    unsigned short* dst = (unsigned short*)&Bt[(wid * 64 + c * 8) * KVBLK];
    __builtin_amdgcn_global_load_lds(
        (const __attribute__((address_space(1))) void*)src,
        (__attribute__((address_space(3))) void*)dst, 16, 0, 0);
  }
  asm volatile("s_waitcnt vmcnt(0)" ::: "memory");
  asm volatile("s_waitcnt lgkmcnt(0)" ::: "memory");
  __builtin_amdgcn_s_barrier();

  const int bbase0 = ((kp * 2) * 4 + (l16 >> 2)) * ROWE + (l16 & 3) * 16 + (g4 & 1) * 8;
  const int bbase1 = bbase0 + 4 * ROWE;   // next kv 16-tile (+16 kv rows)

  for (int kt = 0; kt < NT; ++kt) {
    // ---- swapped QK^T: S^T = K x Q^T; C col = q = l16, row = kv = 4g4+r ----
    f32x4 s0 = {0.f, 0.f, 0.f, 0.f};
    f32x4 s1 = {0.f, 0.f, 0.f, 0.f};
    __builtin_amdgcn_s_setprio(1);
    #pragma unroll
    for (int ks = 0; ks < 16; ++ks) {
      const int ro = (ks * 2 + (g4 >> 1)) * 64;
      const bf16x8 b0 = *reinterpret_cast<const bf16x8*>(&Bs[bbase0 + ro]);
      const bf16x8 b1 = *reinterpret_cast<const bf16x8*>(&Bs[bbase1 + ro]);
      s0 = __builtin_amdgcn_mfma_f32_16x16x32_bf16(b0, qf[ks], s0, 0, 0, 0);
      s1 = __builtin_amdgcn_mfma_f32_16x16x32_bf16(b1, qf[ks], s1, 0, 0, 0);
    }
    __builtin_amdgcn_s_setprio(0);

    // ---- wave-partial max (regs): tree + g4-reduce ----
    {
      float m01 = fmaxf(s0[0], s0[1]), m23 = fmaxf(s0[2], s0[3]);
      float m45 = fmaxf(s1[0], s1[1]), m67 = fmaxf(s1[2], s1[3]);
      float mloc = fmaxf(fmaxf(m01, m23), fmaxf(m45, m67));
      mloc = fmaxf(mloc, __shfl_xor(mloc, 16));
      mloc = fmaxf(mloc, __shfl_xor(mloc, 32));
      if (lane < 16) pmaxS[qi * 32 + kp * 16 + lane] = mloc;
      asm volatile("s_waitcnt lgkmcnt(0)" ::: "memory");
      __builtin_amdgcn_s_barrier();                     // 1: Bs reads done; pmax visible

      // ---- issue Bs(kt+1): lands under exp/PV ----
      if (kt + 1 < NT) {
        const unsigned short* Kt = Kb + (size_t)(kt + 1) * KVBLK * D;
        #pragma unroll
        for (int c = 0; c < 8; ++c) {
          int id = wid * 8 + c;
          int g = id >> 2, q = id & 3;
          const unsigned short* src = Kt
              + (size_t)(g * 4 + ((lane >> 1) & 3)) * D
              + q * 128 + (lane >> 3) * 16 + (lane & 1) * 8;
          unsigned short* dst = &Bs[g * ROWE + q * 512];
          __builtin_amdgcn_global_load_lds(
              (const __attribute__((address_space(1))) void*)src,
              (__attribute__((address_space(3))) void*)dst, 16, 0, 0);
        }
      }

      // ---- combine with partner wave + running max (defer) ----
      float mpart = pmaxS[qi * 32 + (kp ^ 1) * 16 + l16];
      float mcomb = fmaxf(mloc, mpart);
      float mold = mS[qi * 16 + l16];
      int defer = (mcomb <= mold + DEFER_THR) ? 1 : 0;
      float mnew = defer ? mold : mcomb;
      float al = defer ? 1.0f : __expf(mold - mnew);

      // ---- P = exp(S - mnew) in regs; pack kv-contiguous u16x4 ----
      float rowsum = 0.f;
      u16x4 w0, w1;
      #pragma unroll
      for (int r = 0; r < 4; ++r) {
        float p = __expf(s0[r] - mnew);
        rowsum += p;
        w0[r] = f2b(p);
      }
      #pragma unroll
      for (int r = 0; r < 4; ++r) {
        float p = __expf(s1[r] - mnew);
        rowsum += p;
        w1[r] = f2b(p);
      }
      const int prow = (qi * 16 + l16) * PROWP + 32 * kp + 4 * g4;
      *reinterpret_cast<u16x4*>(&Ps[prow])      = w0;
      *reinterpret_cast<u16x4*>(&Ps[prow + 16]) = w1;

      rowsum += __shfl_xor(rowsum, 16);
      rowsum += __shfl_xor(rowsum, 32);
      if (lane < 16) psumS[qi * 32 + kp * 16 + lane] = rowsum;
      int wave_defer = __all(defer);
      if (kp == 0 && lane < 16) {
        mS[qi * 16 + lane] = mnew;
        aS[qi * 16 + lane] = al;
      }
      if (lane == 0) flagS[wid] = wave_defer;

      asm volatile("s_waitcnt lgkmcnt(0)" ::: "memory");
      if (kt + 1 < NT) {
        asm volatile("s_waitcnt vmcnt(8)" ::: "memory");  // Bt(kt) landed
      } else {
        asm volatile("s_waitcnt vmcnt(0)" ::: "memory");
      }
      __builtin_amdgcn_s_barrier();                     // 2: Ps/psum/aS/flags + Bt(kt)

      // ---- lS combine (overlaps PV) ----
      if (kp == 0 && lane < 16) {
        float pp = psumS[qi * 32 + 16 + lane];
        lS[qi * 16 + lane] = lS[qi * 16 + lane] * al + rowsum + pp;
      }
    }

    // ---- conditional rescale + PV: O^T += V^T * P^T (r11 verbatim) ----
    {
      i32x4 f0 = *reinterpret_cast<const i32x4*>(&flagS[0]);
      i32x4 f1 = *reinterpret_cast<const i32x4*>(&flagS[4]);
      int allskip = f0[0] & f0[1] & f0[2] & f0[3] & f1[0] & f1[1] & f1[2] & f1[3];
      if (!allskip) {
        #pragma unroll
        for (int mi = 0; mi < 4; ++mi) {
          float a = aS[mi * 16 + l16];
          #pragma unroll
          for (int ni = 0; ni < 4; ++ni)
            #pragma unroll
            for (int r = 0; r < 4; ++r)
              acc[mi][ni][r] *= a;
        }
      }

      const char* Bc = (const char*)&Bt[0];
      __builtin_amdgcn_s_setprio(1);
      #pragma unroll
      for (int ks = 0; ks < 2; ++ks) {
        bf16x8 pf[4];
        #pragma unroll
        for (int mi = 0; mi < 4; ++mi)
          pf[mi] = *reinterpret_cast<const bf16x8*>(
              &Ps[(mi * 16 + l16) * PROWP + ks * 32 + g4 * 8]);
        #pragma unroll
        for (int ni = 0; ni < 4; ++ni) {
          int row = wid * 64 + ni * 16 + l16;
          int swz = (ks * 4 + g4) ^ (l16 & 7);
          const bf16x8 vf = *reinterpret_cast<const bf16x8*>(Bc + row * 128 + swz * 16);
          #pragma unroll
          for (int mi = 0; mi < 4; ++mi)
            acc[mi][ni] = __builtin_amdgcn_mfma_f32_16x16x32_bf16(vf, pf[mi], acc[mi][ni], 0, 0, 0);
        }
      }
      __builtin_amdgcn_s_setprio(0);
    }
    // own Bt reads complete (Bt is wave-private: no barrier before re-issue)
    asm volatile("s_waitcnt lgkmcnt(0)" ::: "memory");

    // ---- issue Bt(kt+1); wait Bs(kt+1) landed (oldest 8 of 16) ----
    if (kt + 1 < NT) {
      #pragma unroll
      for (int c = 0; c < 8; ++c) {
        int drow = wid * 64 + c * 8 + (lane >> 3);
        int chunk = (lane & 7) ^ ((lane >> 3) & 7);
        const unsigned short* src = Tb + (size_t)drow * NSEQ + (kt + 1) * KVBLK + chunk * 8;
        unsigned short* dst = (unsigned short*)&Bt[(wid * 64 + c * 8) * KVBLK];
        __builtin_amdgcn_global_load_lds(
            (const __attribute__((address_space(1))) void*)src,
            (__attribute__((address_space(3))) void*)dst, 16, 0, 0);
      }
      asm volatile("s_waitcnt vmcnt(8)" ::: "memory");
    }
    __builtin_amdgcn_s_barrier();                       // D: Bs(kt+1) ready
  }

  // ---- epilogue: Out[q][d] = accT/l + A[q][d] (r11 verbatim) ----
  #pragma unroll
  for (int mi = 0; mi < 4; ++mi) {
    float rl = 1.0f / lS[mi * 16 + l16];
    int q = qbase + mi * 16 + l16;
    #pragma unroll
    for (int ni = 0; ni < 4; ++ni) {
      int d = wid * 64 + ni * 16 + g4 * 4;
      const float4 av = *reinterpret_cast<const float4*>(Ab + (size_t)q * D + d);
      float4 o;
      o.x = acc[mi][ni][0] * rl + av.x;
      o.y = acc[mi][ni][1] * rl + av.y;
      o.z = acc[mi][ni][2] * rl + av.z;
      o.w = acc[mi][ni][3] * rl + av.w;
      *reinterpret_cast<float4*>(Ob + (size_t)q * D + d) = o;
    }
  }
}

// ---------- fallback: in-kernel convert staging (no workspace) --------------
#define FQBLK 32
#define FSROWP (64 + 4)
#define FPROWP (64 + 8)
__global__ __launch_bounds__(NTHREADS, 2)
void attn_fb(const float* __restrict__ A, const float* __restrict__ B32,
             float* __restrict__ Out) {
  __shared__ __align__(16) unsigned short Bs[BUFE];
  __shared__ float Ss[FQBLK * FSROWP];
  __shared__ unsigned short Ps[FQBLK * FPROWP];
  __shared__ float mS[FQBLK];
  __shared__ float lS[FQBLK];
  __shared__ float aS[FQBLK];

  const int tid  = threadIdx.x;
  const int wid  = tid >> 6;
  const int lane = tid & 63;
  const int l16  = lane & 15;
  const int g4   = lane >> 4;

  const int batch = blockIdx.x & 7;
  const int qt    = blockIdx.x >> 3;
  const int qbase = qt * FQBLK;

  const float* Ab   = A   + (size_t)batch * NSEQ * D;
  const float* Bb32 = B32 + (size_t)batch * NSEQ * D;
  float*       Ob   = Out + (size_t)batch * NSEQ * D;

  const float scale = 0.04419417382415922f;

  const int qi = wid >> 2;
  const int ki = wid & 3;

  const float* Arow = Ab + (size_t)(qbase + qi * 16 + l16) * D;
  bf16x8 qf[16];
  #pragma unroll
  for (int ks = 0; ks < 16; ++ks) {
    int d0 = ks * 32 + g4 * 8;
    float4 v0 = *reinterpret_cast<const float4*>(Arow + d0);
    float4 v1 = *reinterpret_cast<const float4*>(Arow + d0 + 4);
    bf16x8 f;
    f[0] = (short)f2b(v0.x * scale); f[1] = (short)f2b(v0.y * scale);
    f[2] = (short)f2b(v0.z * scale); f[3] = (short)f2b(v0.w * scale);
    f[4] = (short)f2b(v1.x * scale); f[5] = (short)f2b(v1.y * scale);
    f[6] = (short)f2b(v1.z * scale); f[7] = (short)f2b(v1.w * scale);
    qf[ks] = f;
  }
  if (tid < FQBLK) { mS[tid] = -1e30f; lS[tid] = 0.f; }

  f32x4 acc[2][4];
  #pragma unroll
  for (int mi = 0; mi < 2; ++mi)
    #pragma unroll
    for (int ni = 0; ni < 4; ++ni)
      acc[mi][ni] = (f32x4){0.f, 0.f, 0.f, 0.f};

  for (int kt = 0; kt < NT; ++kt) {
    __builtin_amdgcn_s_barrier();
    const float* Bt2 = Bb32 + (size_t)kt * KVBLK * D;
    #pragma unroll
    for (int c = 0; c < 8; ++c) {
      int id = wid * 8 + c;
      int g = id >> 2, q = id & 3;
      int kv = g * 4 + ((lane >> 1) & 3);
      int d  = q * 128 + (lane >> 3) * 16 + (lane & 1) * 8;
      const float* s = Bt2 + (size_t)kv * D + d;
      float4 v0 = *reinterpret_cast<const float4*>(s);
      float4 v1 = *reinterpret_cast<const float4*>(s + 4);
      bf16x8 h;
      h[0] = (short)f2b(v0.x); h[1] = (short)f2b(v0.y);
      h[2] = (short)f2b(v0.z); h[3] = (short)f2b(v0.w);
      h[4] = (short)f2b(v1.x); h[5] = (short)f2b(v1.y);
      h[6] = (short)f2b(v1.z); h[7] = (short)f2b(v1.w);
      *reinterpret_cast<bf16x8*>(&Bs[g * ROWE + q * 512 + lane * 8]) = h;
    }
    asm volatile("s_waitcnt lgkmcnt(0)" ::: "memory");
    __builtin_amdgcn_s_barrier();

    {
      f32x4 s = {0.f, 0.f, 0.f, 0.f};
      const int bbase = (ki * 4 + (l16 >> 2)) * ROWE + (l16 & 3) * 16 + (g4 & 1) * 8;
      #pragma unroll
      for (int ks = 0; ks < 16; ++ks) {
        const bf16x8 bf = *reinterpret_cast<const bf16x8*>(
            &Bs[bbase + (ks * 2 + (g4 >> 1)) * 64]);
        s = __builtin_amdgcn_mfma_f32_16x16x32_bf16(qf[ks], bf, s, 0, 0, 0);
      }
      #pragma unroll
      for (int r = 0; r < 4; ++r)
        Ss[(qi * 16 + g4 * 4 + r) * FSROWP + ki * 16 + l16] = s[r];
    }
    asm volatile("s_waitcnt lgkmcnt(0)" ::: "memory");
    __builtin_amdgcn_s_barrier();

    {
      int row = wid * 4 + g4;
      float sv[4];
      float mloc = -1e30f;
      #pragma unroll
      for (int j = 0; j < 4; ++j) {
        sv[j] = Ss[row * FSROWP + l16 + 16 * j];
        mloc = fmaxf(mloc, sv[j]);
      }
      #pragma unroll
      for (int off = 1; off < 16; off <<= 1)
        mloc = fmaxf(mloc, __shfl_xor(mloc, off));
      float mold = mS[row];
      float mnew = fmaxf(mold, mloc);
      float al = __expf(mold - mnew);
      float psum = 0.f;
      #pragma unroll
      for (int j = 0; j < 4; ++j) {
        float p = __expf(sv[j] - mnew);
        psum += p;
        Ps[row * FPROWP + l16 + 16 * j] = f2b(p);
      }
      #pragma unroll
      for (int off = 1; off < 16; off <<= 1)
        psum += __shfl_xor(psum, off);
      if (l16 == 0) {
        mS[row] = mnew;
        lS[row] = lS[row] * al + psum;
        aS[row] = al;
      }
    }
    asm volatile("s_waitcnt lgkmcnt(0)" ::: "memory");
    __builtin_amdgcn_s_barrier();

    {
      #pragma unroll
      for (int mi = 0; mi < 2; ++mi)
        #pragma unroll
        for (int r = 0; r < 4; ++r) {
          float a = aS[mi * 16 + g4 * 4 + r];
          #pragma unroll
          for (int ni = 0; ni < 4; ++ni)
            acc[mi][ni][r] *= a;
        }

      #pragma unroll
      for (int ks = 0; ks < 2; ++ks) {
        bf16x8 pf[2];
        #pragma unroll
        for (int mi = 0; mi < 2; ++mi)
          pf[mi] = *reinterpret_cast<const bf16x8*>(
              &Ps[(mi * 16 + l16) * FPROWP + ks * 32 + g4 * 8]);
        #pragma unroll
        for (int ni = 0; ni < 4; ++ni) {
          bf16x8 vv;
          #pragma unroll
          for (int j = 0; j < 8; ++j)
            vv[j] = (short)Bs[(ks * 8 + g4 * 2 + (j >> 2)) * ROWE
                              + (wid * 4 + ni) * 64 + (j & 3) * 16 + l16];
          #pragma unroll
          for (int mi = 0; mi < 2; ++mi)
            acc[mi][ni] = __builtin_amdgcn_mfma_f32_16x16x32_bf16(pf[mi], vv, acc[mi][ni], 0, 0, 0);
        }
      }
    }
  }

  #pragma unroll
  for (int mi = 0; mi < 2; ++mi)
    #pragma unroll
    for (int r = 0; r < 4; ++r) {
      float rl = 1.0f / lS[mi * 16 + g4 * 4 + r];
      #pragma unroll
      for (int ni = 0; ni < 4; ++ni) {
        int q = qbase + mi * 16 + g4 * 4 + r;
        int d = wid * 64 + ni * 16 + l16;
        size_t off = (size_t)q * D + d;
        Ob[off] = acc[mi][ni][r] * rl + Ab[off];
      }
    }
}

extern "C" void kernel_launch(void* const* d_in, const int* in_sizes, int n_in,
                              void* d_out, int out_size, void* d_ws, size_t ws_size,
                              hipStream_t stream) {
  const float* a = (const float*)d_in[0];
  const float* b = (const float*)d_in[1];
  float* out = (float*)d_out;
  const size_t one = (size_t)NB * NSEQ * D * sizeof(unsigned short);  // 16 MB
  dim3 block(NTHREADS);
  if (ws_size >= 2 * one) {
    unsigned short* b16 = (unsigned short*)d_ws;
    unsigned short* bT  = b16 + (size_t)NB * NSEQ * D;
    conv_dual<<<NB * 256, 256, 0, stream>>>(b, b16, bT);
    dim3 grid(NB * (NSEQ / QBLK));            // 256 blocks = 1 per CU
    attn_v18<<<grid, block, 0, stream>>>(a, b16, bT, out);
  } else {
    dim3 grid(NB * (NSEQ / FQBLK));
    attn_fb<<<grid, block, 0, stream>>>(a, b, out);
  }
}